// Round 5
// baseline (65.857 us; speedup 1.0000x reference)
//
#include <hip/hip_runtime.h>

typedef __attribute__((ext_vector_type(8))) short bf16x8;
typedef __attribute__((ext_vector_type(4))) float f32x4;

#define EMB_DIM 400
#define OUT_CH  6
#define ARITY   3
#define BATCH   8192
#define W_OUT   200
#define FC_LEN  1200
#define NT      25        // 16-wide d-tiles (400/16)
#define NKS     7         // k-steps of 32 (K=200 padded to 224)
#define NCHUNK  512       // row-chunks of 16 (8192/16)
#define RG      128       // grid.x of gemm kernel (4 chunks per block)
#define GBLK    2048      // gather blocks in prep
#define PBLK    75        // pack blocks in prep

static __device__ __forceinline__ ushort f2bf(float f) {
    union { float f; uint u; } v; v.f = f;
    uint u = v.u;
    return (ushort)((u + 0x7FFF + ((u >> 16) & 1)) >> 16);   // RNE
}

// ws layout: Mb (bf16 B-frags) at 0, size 3*25*7*512 u16 = 537600 B
//            Af (bf16 A-frags) at 537600, size 512*21*512 u16 = 11010048 B
// B-frag (i,t,kk): lane l, elem j = M_i[w = kk*32+(l>>4)*8+j][d = t*16+(l&15)]
// A-frag (chunk,i,kk): lane l = lsub*16+r, elem j = es[row=chunk*16+r][k=kk*32+lsub*8+j]
__global__ __launch_bounds__(256)
void prep(const int* __restrict__ E_mat, const float* __restrict__ E_emb,
          const float* __restrict__ fc2_W, const float* __restrict__ fc2_b,
          const float* __restrict__ fc_W,
          ushort* __restrict__ Mb, ushort* __restrict__ Af) {
    __shared__ float Bt[224][16];
    const int tid = threadIdx.x;
    if (blockIdx.x < PBLK) {
        // ---- pack_M (proven R2 code) ----
        const int bid = blockIdx.x;            // i*25 + t
        const int i = bid / NT, t = bid % NT;
        float kc[OUT_CH];
#pragma unroll
        for (int c = 0; c < OUT_CH; ++c) kc[c] = fc2_W[c * 4 + i] + fc2_b[c];
        const int dd = tid >> 4, wl = tid & 15;
        const int d = t * 16 + dd;
#pragma unroll
        for (int s = 0; s < 14; ++s) {
            int w = wl + 16 * s;
            float v = 0.f;
            if (w < W_OUT) {
#pragma unroll
                for (int c = 0; c < OUT_CH; ++c)
                    v = fmaf(kc[c], fc_W[d * FC_LEN + c * W_OUT + w], v);
            }
            Bt[w][dd] = v;
        }
        __syncthreads();
        const int l = tid & 63;
        for (int kk = tid >> 6; kk < NKS; kk += 4) {
            ushort vals[8];
#pragma unroll
            for (int j = 0; j < 8; ++j)
                vals[j] = f2bf(Bt[kk * 32 + (l >> 4) * 8 + j][l & 15]);
            *reinterpret_cast<uint4*>(Mb + ((size_t)(bid * NKS + kk) * 64 + l) * 8) =
                *reinterpret_cast<const uint4*>(vals);
        }
    } else {
        // ---- gather E_emb -> bf16 A-fragments ----
        uint* Afu = reinterpret_cast<uint*>(Af);
        const int gtid = (blockIdx.x - PBLK) * 256 + tid;   // 0..524287
        const int GSZ = GBLK * 256;
        const int TOTAL = BATCH * ARITY * 100;              // 2457600 float4 tasks
#pragma unroll
        for (int k = 0; k < 5; ++k) {
            int tq = gtid + k * GSZ;
            if (tq < TOTAL) {
                int q = tq % 100;
                int p = tq / 100;          // b*3 + i
                int i = p % 3, b = p / 3;
                int ent = E_mat[p];
                const float4 v = *reinterpret_cast<const float4*>(
                    E_emb + (size_t)ent * EMB_DIM + 4 * q);
                int w = 2 * q;             // even-col index; covers w, w+1
                int kk = w >> 5;
                int lsub = (w >> 3) & 3;
                int j = w & 7;             // even
                int chunk = b >> 4, r = b & 15;
                int l = lsub * 16 + r;
                uint pk = (uint)f2bf(v.x) | ((uint)f2bf(v.z) << 16);
                Afu[((size_t)(chunk * 3 + i) * 7 + kk) * 256 + l * 4 + (j >> 1)] = pk;
            }
        }
        // zero the K-pad: (chunk,i) x kk=6, lanes 16..63 -> 1536*192 u32
        if (gtid < 1536 * 192) {
            int ci = gtid / 192, rem = gtid % 192;
            int l = 16 + (rem >> 2), jj = rem & 3;
            Afu[((size_t)ci * 7 + 6) * 256 + l * 4 + jj] = 0;
        }
    }
}

__global__ __launch_bounds__(320)
void hype_gemm(const int* __restrict__ r_idx, const float* __restrict__ ms,
               const float* __restrict__ bs, const float* __restrict__ R_emb,
               const float* __restrict__ fc_b, const ushort* __restrict__ Mb,
               const ushort* __restrict__ Af, float* __restrict__ out) {
    __shared__ ushort alds[21 * 512];      // 21504 B: one A-chunk
    const int tid  = threadIdx.x;
    const int wv   = tid >> 6;             // wave 0..4
    const int lane = tid & 63;
    const int cl   = lane & 15;            // d within tile
    const int rql  = lane >> 4;            // row quad
    const int t    = blockIdx.y * 5 + wv;  // this wave's d-tile, 0..24

    // B resident: 21 fragments (84 VGPR)
    bf16x8 bfrag[ARITY][NKS];
#pragma unroll
    for (int i = 0; i < ARITY; ++i)
#pragma unroll
        for (int kk = 0; kk < NKS; ++kk)
            bfrag[i][kk] = *reinterpret_cast<const bf16x8*>(
                Mb + (((size_t)(i * NT + t) * NKS + kk) * 64 + lane) * 8);

    const float fcb = fc_b[t * 16 + cl];

    for (int chunk = blockIdx.x; chunk < NCHUNK; chunk += RG) {
        // stage A-chunk (21504 B) into LDS: 1344 uint4 across 320 threads
        const uint4* src = reinterpret_cast<const uint4*>(Af + (size_t)chunk * 10752);
        uint4* dst = reinterpret_cast<uint4*>(alds);
#pragma unroll
        for (int n = 0; n < 5; ++n) {
            int idx = tid + n * 320;
            if (idx < 1344) dst[idx] = src[idx];
        }
        __syncthreads();

        f32x4 acc[ARITY];
#pragma unroll
        for (int i = 0; i < ARITY; ++i) acc[i] = (f32x4){0.f, 0.f, 0.f, 0.f};
#pragma unroll
        for (int i = 0; i < ARITY; ++i)
#pragma unroll
            for (int kk = 0; kk < NKS; ++kk) {
                bf16x8 a = *reinterpret_cast<const bf16x8*>(
                    alds + ((i * NKS + kk) * 64 + lane) * 8);
                acc[i] = __builtin_amdgcn_mfma_f32_16x16x32_bf16(a, bfrag[i][kk], acc[i], 0, 0, 0);
            }

        const int b0 = chunk * 16;
        float rsum[4];
#pragma unroll
        for (int r_ = 0; r_ < 4; ++r_) {
            int b = b0 + rql * 4 + r_;
            float e0 = fmaf(acc[0][r_] + fcb, ms[b * 3 + 0], bs[b * 3 + 0]);
            float e1 = fmaf(acc[1][r_] + fcb, ms[b * 3 + 1], bs[b * 3 + 1]);
            float e2 = fmaf(acc[2][r_] + fcb, ms[b * 3 + 2], bs[b * 3 + 2]);
            float Rr = R_emb[(size_t)r_idx[b] * EMB_DIM + t * 16 + cl];
            rsum[r_] = e0 * e1 * e2 * Rr;
        }
#pragma unroll
        for (int m = 1; m < 16; m <<= 1)
#pragma unroll
            for (int r_ = 0; r_ < 4; ++r_)
                rsum[r_] += __shfl_xor(rsum[r_], m, 64);
        if (cl == 0) {
#pragma unroll
            for (int r_ = 0; r_ < 4; ++r_)
                atomicAdd(&out[b0 + rql * 4 + r_], rsum[r_]);
        }
        __syncthreads();   // protect alds before next chunk's stage
    }
}

extern "C" void kernel_launch(void* const* d_in, const int* in_sizes, int n_in,
                              void* d_out, int out_size, void* d_ws, size_t ws_size,
                              hipStream_t stream) {
    const int*   r_idx = (const int*)d_in[0];
    const int*   E_mat = (const int*)d_in[1];
    const float* ms    = (const float*)d_in[2];
    const float* bs    = (const float*)d_in[3];
    const float* E_emb = (const float*)d_in[4];
    const float* R_emb = (const float*)d_in[5];
    const float* fc2_W = (const float*)d_in[6];
    const float* fc2_b = (const float*)d_in[7];
    const float* fc_W  = (const float*)d_in[8];
    const float* fc_b  = (const float*)d_in[9];
    float*  out = (float*)d_out;
    ushort* Mb  = (ushort*)d_ws;                       // 537600 B
    ushort* Af  = (ushort*)((char*)d_ws + 537600);     // 11010048 B

    hipMemsetAsync(out, 0, (size_t)out_size * sizeof(float), stream);
    prep<<<PBLK + GBLK, 256, 0, stream>>>(E_mat, E_emb, fc2_W, fc2_b, fc_W, Mb, Af);
    hype_gemm<<<dim3(RG, 5), 320, 0, stream>>>(r_idx, ms, bs, R_emb, fc_b, Mb, Af, out);
}

// Round 6
// 34.079 us; speedup vs baseline: 1.9324x; 1.9324x over previous
//
#include <hip/hip_runtime.h>

typedef __attribute__((ext_vector_type(8))) short bf16x8;
typedef __attribute__((ext_vector_type(4))) float f32x4;

#define EMB_DIM 400
#define OUT_CH  6
#define ARITY   3
#define BATCH   8192
#define W_OUT   200
#define FC_LEN  1200
#define NT      25      // 16-wide col tiles (400/16)
#define NKS     7       // k-steps of 32 (K=200 padded to 224)
#define BM      32      // batch rows per block
#define NTASK   (ARITY * BM * 100)   // 9600 float4 gather tasks per block
#define NLD     19                   // ceil(NTASK / 512)

static __device__ __forceinline__ ushort f2bf(float f) {
    union { float f; uint u; } v; v.f = f;
    uint u = v.u;
    return (ushort)((u + 0x7FFF + ((u >> 16) & 1)) >> 16);   // RNE
}

// Mb layout: for (i*NT+t, kk): 64 lanes x 8 bf16; lane l, elem j holds
//   B[w = kk*32 + (l>>4)*8 + j][d = t*16 + (l&15)]  (w>=200 -> 0)
// grid (75, 7): x = i*25+t, y = kk (one 32-wide w-slice per block)
__global__ __launch_bounds__(256)
void pack_M(const float* __restrict__ fc2_W, const float* __restrict__ fc2_b,
            const float* __restrict__ fc_W, ushort* __restrict__ Mb) {
    __shared__ float Bt[32][16];
    const int bid = blockIdx.x;            // i*25 + t
    const int kk  = blockIdx.y;
    const int i = bid / NT, t = bid % NT;
    float kc[OUT_CH];
#pragma unroll
    for (int c = 0; c < OUT_CH; ++c) kc[c] = fc2_W[c * 4 + i] + fc2_b[c];
    const int tid = threadIdx.x;
    const int dd = tid >> 4, wl = tid & 15;
    const int d = t * 16 + dd;
#pragma unroll
    for (int s = 0; s < 2; ++s) {
        int w = kk * 32 + wl + 16 * s;
        float v = 0.f;
        if (w < W_OUT) {
#pragma unroll
            for (int c = 0; c < OUT_CH; ++c)
                v = fmaf(kc[c], fc_W[d * FC_LEN + c * W_OUT + w], v);
        }
        Bt[wl + 16 * s][dd] = v;
    }
    __syncthreads();
    if (tid < 64) {
        const int l = tid;
        ushort vals[8];
#pragma unroll
        for (int j = 0; j < 8; ++j)
            vals[j] = f2bf(Bt[(l >> 4) * 8 + j][l & 15]);
        *reinterpret_cast<uint4*>(Mb + ((size_t)(bid * NKS + kk) * 64 + l) * 8) =
            *reinterpret_cast<const uint4*>(vals);
    }
}

__global__ __launch_bounds__(512)
void hype_mfma(const int* __restrict__ r_idx, const int* __restrict__ E_mat,
               const float* __restrict__ ms, const float* __restrict__ bs,
               const float* __restrict__ E_emb, const float* __restrict__ R_emb,
               const float* __restrict__ fc_b, const ushort* __restrict__ Mb,
               float* __restrict__ out) {
    // es: A-fragments. chunk (i, rg, kk) = 64 lanes * 16B, lane-linear.
    __shared__ ushort es[ARITY * 2 * NKS * 64 * 8];   // 43008 B
    __shared__ float sm_ms[BM * 3], sm_bs[BM * 3], sm_fcb[EMB_DIM];
    __shared__ int   sm_rb[BM], sm_ent[BM * 3];
    __shared__ float osum[4][BM];

    const int tid = threadIdx.x;
    const int b0 = blockIdx.x * BM;

    if (tid < BM * 3) {
        sm_ms[tid]  = ms[b0 * 3 + tid];
        sm_bs[tid]  = bs[b0 * 3 + tid];
        sm_ent[tid] = E_mat[b0 * 3 + tid];
    }
    if (tid >= 96 && tid < 96 + BM) sm_rb[tid - 96] = r_idx[b0 + tid - 96] * EMB_DIM;
    for (int z = tid; z < EMB_DIM; z += 512) sm_fcb[z] = fc_b[z];

    uint* esu = reinterpret_cast<uint*>(es);
    // zero the K-pad: kk=6, lane>=16 regions: 6 pairs * 192 uints
    for (int z = tid; z < ARITY * 2 * 192; z += 512) {
        int pair = z / 192, off = z % 192;
        esu[(pair * NKS + 6) * 256 + 64 + off] = 0;
    }
    __syncthreads();   // sm_ent ready

    // ---- batched gather: issue ALL 19 random loads before any conversion ----
    float4 vreg[NLD];
#pragma unroll
    for (int k = 0; k < NLD; ++k) {
        int tq = tid + k * 512;
        if (tq < NTASK) {
            int q = tq % 100;
            int p = tq / 100;
            int i = p / BM, r = p % BM;
            int ent = sm_ent[r * 3 + i];
            vreg[k] = *reinterpret_cast<const float4*>(
                E_emb + (size_t)ent * EMB_DIM + 4 * q);
        }
    }
#pragma unroll
    for (int k = 0; k < NLD; ++k) {
        int tq = tid + k * 512;
        if (tq < NTASK) {
            int q = tq % 100;
            int p = tq / 100;
            int i = p / BM, r = p % BM;
            int w = 2 * q;                    // covers w, w+1 (same 8-block)
            int kk = w >> 5;
            int lsub = (w >> 3) & 3;
            int j = w & 7;                    // even
            int rg = r >> 4, rl = r & 15;
            int l = lsub * 16 + rl;
            uint pk = (uint)f2bf(vreg[k].x) | ((uint)f2bf(vreg[k].z) << 16);
            esu[(((i * 2 + rg) * NKS + kk) * 64 + l) * 4 + (j >> 1)] = pk;
        }
    }
    __syncthreads();

    const int wid = tid >> 6;
    const int lane = tid & 63;
    const int rg = wid & 1, cg = wid >> 1;     // rg: row-group, cg: col-group
    const int cl = lane & 15;                   // col within tile
    const int rql = lane >> 4;                  // row quad

    // preload all A fragments for this wave's 16 rows (3 i * 7 kk)
    bf16x8 afrag[ARITY][NKS];
#pragma unroll
    for (int i = 0; i < ARITY; ++i)
#pragma unroll
        for (int kk = 0; kk < NKS; ++kk)
            afrag[i][kk] = *reinterpret_cast<const bf16x8*>(
                es + (((i * 2 + rg) * NKS + kk) * 64 + lane) * 8);

    float msv[ARITY][4], bsv[ARITY][4];
    int rbv[4];
#pragma unroll
    for (int r_ = 0; r_ < 4; ++r_) {
        int row = rg * 16 + rql * 4 + r_;
#pragma unroll
        for (int i = 0; i < ARITY; ++i) {
            msv[i][r_] = sm_ms[row * 3 + i];
            bsv[i][r_] = sm_bs[row * 3 + i];
        }
        rbv[r_] = sm_rb[row];
    }

    float rowsum[4] = {0.f, 0.f, 0.f, 0.f};
    for (int t = cg; t < NT; t += 4) {
        f32x4 acc[ARITY];
#pragma unroll
        for (int i = 0; i < ARITY; ++i) {
            f32x4 a = {0.f, 0.f, 0.f, 0.f};
            const ushort* bp = Mb + ((size_t)(i * NT + t) * NKS * 64 + lane) * 8;
#pragma unroll
            for (int kk = 0; kk < NKS; ++kk) {
                bf16x8 bfr = *reinterpret_cast<const bf16x8*>(bp + kk * 512);
                a = __builtin_amdgcn_mfma_f32_16x16x32_bf16(afrag[i][kk], bfr, a, 0, 0, 0);
            }
            acc[i] = a;
        }
        const int d = t * 16 + cl;
        const float fcb = sm_fcb[d];
#pragma unroll
        for (int r_ = 0; r_ < 4; ++r_) {
            float Rr = R_emb[rbv[r_] + d];
            float e0 = fmaf(acc[0][r_] + fcb, msv[0][r_], bsv[0][r_]);
            float e1 = fmaf(acc[1][r_] + fcb, msv[1][r_], bsv[1][r_]);
            float e2 = fmaf(acc[2][r_] + fcb, msv[2][r_], bsv[2][r_]);
            rowsum[r_] = fmaf(e0 * e1 * e2, Rr, rowsum[r_]);
        }
    }

#pragma unroll
    for (int m = 1; m < 16; m <<= 1)
#pragma unroll
        for (int r_ = 0; r_ < 4; ++r_)
            rowsum[r_] += __shfl_xor(rowsum[r_], m, 64);
    if (cl == 0) {
#pragma unroll
        for (int r_ = 0; r_ < 4; ++r_)
            osum[cg][rg * 16 + rql * 4 + r_] = rowsum[r_];
    }
    __syncthreads();
    if (tid < BM)
        out[b0 + tid] = osum[0][tid] + osum[1][tid] + osum[2][tid] + osum[3][tid];
}

extern "C" void kernel_launch(void* const* d_in, const int* in_sizes, int n_in,
                              void* d_out, int out_size, void* d_ws, size_t ws_size,
                              hipStream_t stream) {
    const int*   r_idx = (const int*)d_in[0];
    const int*   E_mat = (const int*)d_in[1];
    const float* ms    = (const float*)d_in[2];
    const float* bs    = (const float*)d_in[3];
    const float* E_emb = (const float*)d_in[4];
    const float* R_emb = (const float*)d_in[5];
    const float* fc2_W = (const float*)d_in[6];
    const float* fc2_b = (const float*)d_in[7];
    const float* fc_W  = (const float*)d_in[8];
    const float* fc_b  = (const float*)d_in[9];
    float*  out = (float*)d_out;
    ushort* Mb  = (ushort*)d_ws;     // 3*25*7*64*8*2 = 537600 B

    pack_M<<<dim3(ARITY * NT, NKS), 256, 0, stream>>>(fc2_W, fc2_b, fc_W, Mb);
    hype_mfma<<<BATCH / BM, 512, 0, stream>>>(r_idx, E_mat, ms, bs, E_emb, R_emb,
                                              fc_b, Mb, out);
}